// Round 1
// baseline (1724.926 us; speedup 1.0000x reference)
//
#include <hip/hip_runtime.h>
#include <math.h>

// Problem constants
#define BATCH 4
#define NF 64
#define GRP 8
#define CG 8
#define H_ 96
#define W_ 96
#define HW_ (96*96)
#define N1 (4*64*96*96)      // 2359296 floats per [B,64,96,96] tensor
#define NOM (4*216*96*96)    // 7962624 floats for om

// ---------------------------------------------------------------------------
// Bilinear x2 upsample, PyTorch align_corners=False semantics, with scale.
// in: [B,64,48,48] -> out: [B,64,96,96]
__global__ __launch_bounds__(256) void up2_k(const float* __restrict__ in,
                                             float* __restrict__ out,
                                             float scale) {
    int idx = blockIdx.x * 256 + threadIdx.x;
    if (idx >= N1) return;
    int x = idx % 96;
    int y = (idx / 96) % 96;
    int bc = idx / HW_;
    float sy = fmaxf(y * 0.5f - 0.25f, 0.f);
    float sx = fmaxf(x * 0.5f - 0.25f, 0.f);
    int y0 = (int)sy; float ty = sy - (float)y0; int y1 = min(y0 + 1, 47);
    int x0 = (int)sx; float tx = sx - (float)x0; int x1 = min(x0 + 1, 47);
    const float* p = in + (size_t)bc * (48 * 48);
    float v00 = p[y0 * 48 + x0], v01 = p[y0 * 48 + x1];
    float v10 = p[y1 * 48 + x0], v11 = p[y1 * 48 + x1];
    float v = (v00 * (1.f - tx) + v01 * tx) * (1.f - ty)
            + (v10 * (1.f - tx) + v11 * tx) * ty;
    out[idx] = v * scale;
}

// ---------------------------------------------------------------------------
// Direct 3x3 conv, stride1 pad1, input = concat(in1[cin1], in2[cin_total-cin1]).
// Block: 256 threads = 16x16 output tile. Each thread accumulates CHUNK out chans.
// grid = (36 tiles, B, cout_total/CHUNK)
template<int CHUNK, bool LRELU>
__global__ __launch_bounds__(256) void conv3x3_k(
        const float* __restrict__ in1, const float* __restrict__ in2,
        int cin1, int cin_total,
        const float* __restrict__ w, const float* __restrict__ bias,
        float* __restrict__ out, int cout_total) {
    __shared__ float s_in[2][18][20];
    __shared__ float s_w[CHUNK][2][9];

    int tid = threadIdx.x;
    int tx = tid & 15, ty = tid >> 4;
    int tile = blockIdx.x;
    int bx = (tile % 6) * 16, by = (tile / 6) * 16;
    int bb = blockIdx.y;
    int oc0 = blockIdx.z * CHUNK;

    float acc[CHUNK];
#pragma unroll
    for (int o = 0; o < CHUNK; ++o) acc[o] = 0.f;

    for (int c0 = 0; c0 < cin_total; c0 += 2) {
        // stage two input-channel tiles (with halo, zero-padded)
#pragma unroll
        for (int cc = 0; cc < 2; ++cc) {
            int c = c0 + cc;
            const float* src = (c < cin1)
                ? (in1 + ((size_t)bb * cin1 + c) * HW_)
                : (in2 + ((size_t)bb * (cin_total - cin1) + (c - cin1)) * HW_);
            for (int i = tid; i < 18 * 18; i += 256) {
                int r = i / 18, cl = i % 18;
                int gy = by - 1 + r, gx = bx - 1 + cl;
                float v = 0.f;
                if ((unsigned)gy < 96u && (unsigned)gx < 96u) v = src[gy * 96 + gx];
                s_in[cc][r][cl] = v;
            }
        }
        // stage weights for these 2 channels x CHUNK outputs
        for (int i = tid; i < CHUNK * 18; i += 256) {
            int o = i / 18, rem = i % 18, cc = rem / 9, k = rem % 9;
            s_w[o][cc][k] = w[(((size_t)(oc0 + o)) * cin_total + (c0 + cc)) * 9 + k];
        }
        __syncthreads();

        float v[2][9];
#pragma unroll
        for (int cc = 0; cc < 2; ++cc)
#pragma unroll
            for (int ky = 0; ky < 3; ++ky)
#pragma unroll
                for (int kx = 0; kx < 3; ++kx)
                    v[cc][ky * 3 + kx] = s_in[cc][ty + ky][tx + kx];

#pragma unroll
        for (int o = 0; o < CHUNK; ++o) {
            float a = acc[o];
#pragma unroll
            for (int cc = 0; cc < 2; ++cc)
#pragma unroll
                for (int k = 0; k < 9; ++k)
                    a += v[cc][k] * s_w[o][cc][k];
            acc[o] = a;
        }
        __syncthreads();
    }

    int y = by + ty, x = bx + tx;
#pragma unroll
    for (int o = 0; o < CHUNK; ++o) {
        float r = acc[o] + bias[oc0 + o];
        if (LRELU) r = (r >= 0.f) ? r : 0.1f * r;
        out[(((size_t)bb * cout_total + oc0 + o) * 96 + y) * 96 + x] = r;
    }
}

// ---------------------------------------------------------------------------
// Modulated deformable conv (DCNv2), 3x3, deformable groups = 8, conv groups = 1.
// x: src0 [B,64,96,96]; om: [B,216,96,96] (off_y | off_x | mask-logits);
// wd: [64,64,9]; out: [B,64,96,96]
__global__ __launch_bounds__(256) void dcn_k(const float* __restrict__ x,
                                             const float* __restrict__ om,
                                             const float* __restrict__ wd,
                                             const float* __restrict__ bd,
                                             float* __restrict__ out) {
    __shared__ float s_w[64 * 72];   // per g: [o][cg*9+kk], 18 KB

    int tid = threadIdx.x;
    int tx = tid & 15, ty = tid >> 4;
    int tile = blockIdx.x;
    int bx = (tile % 6) * 16, by = (tile / 6) * 16;
    int bb = blockIdx.y;
    int y = by + ty, xx = bx + tx;

    float acc[64];
#pragma unroll
    for (int o = 0; o < 64; ++o) acc[o] = 0.f;

    for (int g = 0; g < 8; ++g) {
        __syncthreads();
        for (int i = tid; i < 4608; i += 256) {
            // i = o*72 + (cg*9+kk);  w_dcn[(o*64 + g*8 + cg)*9 + kk]
            int o = i / 72, rem = i % 72;
            s_w[i] = wd[((size_t)o * 64 + g * 8) * 9 + rem];
        }
        __syncthreads();

        const float* xg = x + ((size_t)bb * 64 + g * 8) * HW_;

        for (int kk = 0; kk < 9; ++kk) {
            int ch = g * 9 + kk;
            size_t base = ((size_t)bb * 216 + ch) * HW_ + (size_t)y * 96 + xx;
            float oy = om[base];
            float ox = om[base + (size_t)72 * HW_];
            float m  = om[base + (size_t)144 * HW_];
            m = 1.f / (1.f + __expf(-m));

            float py = oy + (float)y + (float)(kk / 3 - 1);
            float px = ox + (float)xx + (float)(kk % 3 - 1);
            float y0f = floorf(py), x0f = floorf(px);
            float fy = py - y0f, fx = px - x0f;
            int iy0 = (int)y0f, ix0 = (int)x0f;
            int iy1 = iy0 + 1, ix1 = ix0 + 1;
            float vy0 = ((unsigned)iy0 < 96u) ? 1.f : 0.f;
            float vy1 = ((unsigned)iy1 < 96u) ? 1.f : 0.f;
            float vx0 = ((unsigned)ix0 < 96u) ? 1.f : 0.f;
            float vx1 = ((unsigned)ix1 < 96u) ? 1.f : 0.f;
            int cy0 = min(max(iy0, 0), 95), cy1 = min(max(iy1, 0), 95);
            int cx0 = min(max(ix0, 0), 95), cx1 = min(max(ix1, 0), 95);
            float w00 = (1.f - fy) * (1.f - fx) * vy0 * vx0;
            float w01 = (1.f - fy) * fx         * vy0 * vx1;
            float w10 = fy * (1.f - fx)         * vy1 * vx0;
            float w11 = fy * fx                 * vy1 * vx1;
            int i00 = cy0 * 96 + cx0, i01 = cy0 * 96 + cx1;
            int i10 = cy1 * 96 + cx0, i11 = cy1 * 96 + cx1;

            float vm[8];
#pragma unroll
            for (int cg = 0; cg < 8; ++cg) {
                const float* p = xg + (size_t)cg * HW_;
                vm[cg] = (w00 * p[i00] + w01 * p[i01] +
                          w10 * p[i10] + w11 * p[i11]) * m;
            }
#pragma unroll
            for (int o = 0; o < 64; ++o) {
                float a = acc[o];
#pragma unroll
                for (int cg = 0; cg < 8; ++cg)
                    a += vm[cg] * s_w[o * 72 + cg * 9 + kk];
                acc[o] = a;
            }
        }
    }

#pragma unroll
    for (int o = 0; o < 64; ++o)
        out[(((size_t)bb * 64 + o) * 96 + y) * 96 + xx] = acc[o] + bd[o];
}

// ---------------------------------------------------------------------------
extern "C" void kernel_launch(void* const* d_in, const int* in_sizes, int n_in,
                              void* d_out, int out_size, void* d_ws, size_t ws_size,
                              hipStream_t stream) {
    const float* src0   = (const float*)d_in[0];
    const float* src1   = (const float*)d_in[1];
    const float* l_off  = (const float*)d_in[2];
    const float* l_fea  = (const float*)d_in[3];
    const float* w1 = (const float*)d_in[4];   const float* b1 = (const float*)d_in[5];
    const float* w2 = (const float*)d_in[6];   const float* b2 = (const float*)d_in[7];
    const float* w3 = (const float*)d_in[8];   const float* b3 = (const float*)d_in[9];
    const float* wom = (const float*)d_in[10]; const float* bom = (const float*)d_in[11];
    const float* wd = (const float*)d_in[12];  const float* bd = (const float*)d_in[13];
    const float* wf = (const float*)d_in[14];  const float* bf = (const float*)d_in[15];

    float* ws   = (float*)d_ws;
    float* pA   = ws;                 // offset1
    float* pB   = ws + (size_t)N1;    // up2(last_offset)*2
    float* pC   = ws + 2 * (size_t)N1;// offset2
    float* pOM  = ws;                 // om (reuses A/B/C after they die)
    float* pDCN = ws + (size_t)NOM;   // dcn feature
    float* pLF  = ws;                 // up2(last_feature) (reuses om after dcn)

    float* out_off = (float*)d_out;          // output 0: offset
    float* out_fea = out_off + (size_t)N1;   // output 1: feature

    const int upBlocks = (N1 + 255) / 256;

    // 1. lo = up2(last_offset) * 2
    up2_k<<<upBlocks, 256, 0, stream>>>(l_off, pB, 2.0f);
    // 2. offset1 = lrelu(conv(concat(src0, src1)))
    conv3x3_k<16, true><<<dim3(36, 4, 4), 256, 0, stream>>>(
        src0, src1, 64, 128, w1, b1, pA, 64);
    // 3. offset2 = lrelu(conv(concat(offset1, lo)))
    conv3x3_k<16, true><<<dim3(36, 4, 4), 256, 0, stream>>>(
        pA, pB, 64, 128, w2, b2, pC, 64);
    // 4. offset = lrelu(conv(offset2))  -> output 0
    conv3x3_k<16, true><<<dim3(36, 4, 4), 256, 0, stream>>>(
        pC, nullptr, 64, 64, w3, b3, out_off, 64);
    // 5. om = conv(offset)  (216 channels)
    conv3x3_k<27, false><<<dim3(36, 4, 8), 256, 0, stream>>>(
        out_off, nullptr, 64, 64, wom, bom, pOM, 216);
    // 6. dcn feature
    dcn_k<<<dim3(36, 4), 256, 0, stream>>>(src0, pOM, wd, bd, pDCN);
    // 7. lf = up2(last_feature)   (om region now dead)
    up2_k<<<upBlocks, 256, 0, stream>>>(l_fea, pLF, 1.0f);
    // 8. feature = lrelu(conv(concat(dcn, lf)))  -> output 1
    conv3x3_k<16, true><<<dim3(36, 4, 4), 256, 0, stream>>>(
        pDCN, pLF, 64, 128, wf, bf, out_fea, 64);
}

// Round 2
// 385.094 us; speedup vs baseline: 4.4792x; 4.4792x over previous
//
#include <hip/hip_runtime.h>
#include <math.h>

typedef __attribute__((ext_vector_type(8))) short bf16x8;
typedef __attribute__((ext_vector_type(4))) float f32x4;
typedef __attribute__((ext_vector_type(4))) int int4v;

__device__ __forceinline__ ushort f2bf(float f) {
    union { float f; unsigned u; } v; v.f = f;
    unsigned r = (v.u + 0x7fffu + ((v.u >> 16) & 1u)) >> 16;
    return (ushort)r;
}
__device__ __forceinline__ float bf2f(ushort h) {
    union { unsigned u; float f; } v; v.u = ((unsigned)h) << 16;
    return v.f;
}

// ---------------------------------------------------------------------------
// Pack concat(src0,src1) fp32 NCHW -> bf16 channels-last [b][px][128]
__global__ __launch_bounds__(256) void pack2_k(const float* __restrict__ s0,
        const float* __restrict__ s1, ushort* __restrict__ xo) {
    int b = blockIdx.y;
    int px = blockIdx.x * 64 + (threadIdx.x & 63);
    int u = threadIdx.x >> 6;
    for (int half = 0; half < 2; ++half) {
        int cg = u + half * 4;            // 0..7 (16 ch each)
        alignas(16) ushort tmp[16];
        for (int i = 0; i < 16; ++i) {
            int c = cg * 16 + i;
            float v = (c < 64) ? s0[((size_t)(b * 64 + c)) * 9216 + px]
                               : s1[((size_t)(b * 64 + c - 64)) * 9216 + px];
            tmp[i] = f2bf(v);
        }
        ushort* dst = xo + ((size_t)(b * 9216) + px) * 128 + cg * 16;
        *(int4v*)dst = *(int4v*)&tmp[0];
        *(int4v*)(dst + 8) = *(int4v*)&tmp[8];
    }
}

// ---------------------------------------------------------------------------
// Bilinear x2 upsample (PyTorch align_corners=False) -> bf16 ch-last slice
__global__ __launch_bounds__(256) void up2chl_k(const float* __restrict__ in,
        ushort* __restrict__ xo, int ochs, int ocoff, float scale) {
    int b = blockIdx.y;
    int px = blockIdx.x * 64 + (threadIdx.x & 63);
    int cg = threadIdx.x >> 6;            // 0..3 (16 ch each)
    int y = px / 96, x = px % 96;
    float sy = fmaxf(y * 0.5f - 0.25f, 0.f);
    float sx = fmaxf(x * 0.5f - 0.25f, 0.f);
    int y0 = (int)sy, x0 = (int)sx;
    float ty = sy - (float)y0, tx = sx - (float)x0;
    int y1 = min(y0 + 1, 47), x1 = min(x0 + 1, 47);
    alignas(16) ushort tmp[16];
    for (int i = 0; i < 16; ++i) {
        int c = cg * 16 + i;
        const float* p = in + ((size_t)(b * 64 + c)) * 2304;
        float v00 = p[y0 * 48 + x0], v01 = p[y0 * 48 + x1];
        float v10 = p[y1 * 48 + x0], v11 = p[y1 * 48 + x1];
        float v = (v00 * (1.f - tx) + v01 * tx) * (1.f - ty)
                + (v10 * (1.f - tx) + v11 * tx) * ty;
        tmp[i] = f2bf(v * scale);
    }
    ushort* dst = xo + ((size_t)(b * 9216) + px) * ochs + ocoff + cg * 16;
    *(int4v*)dst = *(int4v*)&tmp[0];
    *(int4v*)(dst + 8) = *(int4v*)&tmp[8];
}

// ---------------------------------------------------------------------------
// Weight prepack: w[oc][cin][3][3] fp32 -> wp[cc][kk][kg][CoutP][8] bf16
__global__ __launch_bounds__(256) void prepw_k(const float* __restrict__ w,
        ushort* __restrict__ wp, int Cin, int CoutR, int CoutP, int units) {
    int u = blockIdx.x * 256 + threadIdx.x;
    if (u >= units) return;
    int oc = u % CoutP; int t = u / CoutP;
    int kg = t & 3; t >>= 2;
    int kk = t % 9; int cc = t / 9;
    alignas(16) ushort tmp[8];
    for (int j = 0; j < 8; ++j) {
        int c = cc * 32 + kg * 8 + j;
        float v = (oc < CoutR) ? w[((size_t)oc * Cin + c) * 9 + kk] : 0.f;
        tmp[j] = f2bf(v);
    }
    *(int4v*)(wp + (size_t)u * 8) = *(int4v*)tmp;
}

// DCN weight prepack: wd[oc][64][3][3] -> wdp[gkk*64+oc][8], k=(g*9+kk)*8+cg
__global__ __launch_bounds__(256) void prepwd_k(const float* __restrict__ wd,
        ushort* __restrict__ wp) {
    int u = blockIdx.x * 256 + threadIdx.x;   // units = 72*64 = 4608
    if (u >= 4608) return;
    int oc = u & 63; int gkk = u >> 6;
    int g = gkk / 9, kk = gkk % 9;
    alignas(16) ushort tmp[8];
    for (int j = 0; j < 8; ++j)
        tmp[j] = f2bf(wd[((size_t)oc * 64 + g * 8 + j) * 9 + kk]);
    *(int4v*)(wp + (size_t)u * 8) = *(int4v*)tmp;
}

// ---------------------------------------------------------------------------
// MFMA 3x3 conv: ch-last bf16 in, per-wave 64oc x 16px, block = 8x8 px tile.
// grid = (144, B, CoutP/64)
template<int CIN, bool LRELU, bool ST_F32, bool ST_NB16, bool ST_CHL>
__global__ __launch_bounds__(256) void conv_mfma_k(
        const ushort* __restrict__ xin,      // [b][9216][CIN] bf16
        const ushort* __restrict__ wp,       // [CIN/32][9][4][CoutP][8]
        const float* __restrict__ bias,
        float* __restrict__ outf,            // NCHW fp32
        ushort* __restrict__ outnb,          // NCHW bf16
        ushort* __restrict__ chl,            // ch-last bf16
        int CoutR, int CoutP, int ochs, int ocoff) {
    constexpr int CC = CIN / 32;
    __shared__ ushort s_act[4000];            // [100 px][40] (32 used + pad)
    __shared__ ushort s_w[19584];             // [(kk*4+kg)*68 + oc][8]

    int tid = threadIdx.x;
    int wv = tid >> 6, ln = tid & 63;
    int l15 = ln & 15, l4 = ln >> 4;
    int tile = blockIdx.x;
    int b = blockIdx.y;
    int bx = (tile % 12) * 8, by = (tile / 12) * 8;
    int oc0 = blockIdx.z * 64;
    int mtn = min(4, (CoutP - oc0) >> 4);
    int ocn = mtn << 4;

    int px_l = wv * 16 + l15;                 // px in 8x8 tile
    int py = px_l >> 3, pxx = px_l & 7;
    int b_base = (py * 10 + pxx) * 40 + l4 * 8;

    f32x4 acc[4];
#pragma unroll
    for (int mt = 0; mt < 4; ++mt) acc[mt] = (f32x4){0.f, 0.f, 0.f, 0.f};

    for (int cc = 0; cc < CC; ++cc) {
        __syncthreads();
        // stage activation halo tile 10x10 x 32ch
        for (int i = tid; i < 400; i += 256) {
            int p = i >> 2, q = i & 3;
            int gy = by + (p / 10) - 1, gx = bx + (p % 10) - 1;
            int4v v = {0, 0, 0, 0};
            if ((unsigned)gy < 96u && (unsigned)gx < 96u)
                v = *(const int4v*)(xin +
                    ((size_t)(b * 9216 + gy * 96 + gx) * CIN + cc * 32 + q * 8));
            *(int4v*)(s_act + p * 40 + q * 8) = v;
        }
        // stage weights for this cc / oc block
        for (int i = tid; i < 36 * ocn; i += 256) {
            int kk = i / (4 * ocn); int r = i - kk * 4 * ocn;
            int kg = r / ocn; int oc = r - kg * ocn;
            int4v v = *(const int4v*)(wp +
                ((size_t)((cc * 9 + kk) * 4 + kg) * CoutP + oc0 + oc) * 8);
            *(int4v*)(s_w + ((kk * 4 + kg) * 68 + oc) * 8) = v;
        }
        __syncthreads();
#pragma unroll
        for (int kk = 0; kk < 9; ++kk) {
            bf16x8 bfrag = *(const bf16x8*)(s_act + b_base +
                               ((kk / 3) * 10 + (kk % 3)) * 40);
#pragma unroll
            for (int mt = 0; mt < 4; ++mt) {
                if (mt < mtn) {
                    bf16x8 af = *(const bf16x8*)(s_w +
                        ((kk * 4 + l4) * 68 + mt * 16 + l15) * 8);
                    acc[mt] = __builtin_amdgcn_mfma_f32_16x16x32_bf16(
                        af, bfrag, acc[mt], 0, 0, 0);
                }
            }
        }
    }

    int gy = by + py, gx = bx + pxx;
    size_t pxg = (size_t)b * 9216 + gy * 96 + gx;
#pragma unroll
    for (int mt = 0; mt < 4; ++mt) {
        if (mt < mtn) {
            ushort hb[4];
#pragma unroll
            for (int r = 0; r < 4; ++r) {
                int oc = oc0 + mt * 16 + l4 * 4 + r;
                float v = acc[mt][r] + ((oc < CoutR) ? bias[oc] : 0.f);
                if (LRELU) v = (v >= 0.f) ? v : 0.1f * v;
                hb[r] = f2bf(v);
                if (ST_F32 && oc < CoutR)
                    outf[((size_t)b * CoutR + oc) * 9216 + gy * 96 + gx] = v;
                if (ST_NB16 && oc < CoutR)
                    outnb[((size_t)b * CoutR + oc) * 9216 + gy * 96 + gx] = hb[r];
            }
            if (ST_CHL) {
                uint2 pk;
                pk.x = (uint)hb[0] | ((uint)hb[1] << 16);
                pk.y = (uint)hb[2] | ((uint)hb[3] << 16);
                *(uint2*)(chl + pxg * ochs + ocoff + oc0 + mt * 16 + l4 * 4) = pk;
            }
        }
    }
}

// ---------------------------------------------------------------------------
// Fused DCNv2: per-wave sampling of one gkk slice into LDS, then MFMA GEMM.
// K order: k = (g*9+kk)*8 + cg, 18 k-steps of 32. grid = (144, B)
__global__ __launch_bounds__(256) void dcn_fused_k(const float* __restrict__ x,
        const ushort* __restrict__ om, const ushort* __restrict__ wdp,
        const float* __restrict__ bd, ushort* __restrict__ chl) {
    __shared__ ushort s_cols[64 * 40];        // [px][40] (32 used + pad)
    int tid = threadIdx.x;
    int wv = tid >> 6, ln = tid & 63;
    int l15 = ln & 15, l4 = ln >> 4;
    int b = blockIdx.y;
    int px0 = blockIdx.x * 64;
    int px = px0 + ln;
    int y = px / 96, xx = px % 96;

    f32x4 acc[4];
#pragma unroll
    for (int mt = 0; mt < 4; ++mt) acc[mt] = (f32x4){0.f, 0.f, 0.f, 0.f};
    const float* xb = x + (size_t)b * 64 * 9216;

    for (int ks = 0; ks < 18; ++ks) {
        __syncthreads();
        int gkk = ks * 4 + wv;                // wave-uniform
        int g = gkk / 9, kk = gkk % 9;
        size_t ob = ((size_t)b * 216 + gkk) * 9216 + px;
        float oy = bf2f(om[ob]);
        float ox = bf2f(om[ob + (size_t)72 * 9216]);
        float mm = bf2f(om[ob + (size_t)144 * 9216]);
        mm = 1.f / (1.f + __expf(-mm));
        float py = oy + (float)y + (float)(kk / 3 - 1);
        float pxf = ox + (float)xx + (float)(kk % 3 - 1);
        float yf = floorf(py), xf = floorf(pxf);
        float fy = py - yf, fx = pxf - xf;
        int iy0 = (int)yf, ix0 = (int)xf;
        int iy1 = iy0 + 1, ix1 = ix0 + 1;
        float vy0 = ((unsigned)iy0 < 96u) ? 1.f : 0.f;
        float vy1 = ((unsigned)iy1 < 96u) ? 1.f : 0.f;
        float vx0 = ((unsigned)ix0 < 96u) ? 1.f : 0.f;
        float vx1 = ((unsigned)ix1 < 96u) ? 1.f : 0.f;
        int cy0 = min(max(iy0, 0), 95), cy1 = min(max(iy1, 0), 95);
        int cx0 = min(max(ix0, 0), 95), cx1 = min(max(ix1, 0), 95);
        float w00 = (1.f - fy) * (1.f - fx) * vy0 * vx0;
        float w01 = (1.f - fy) * fx         * vy0 * vx1;
        float w10 = fy * (1.f - fx)         * vy1 * vx0;
        float w11 = fy * fx                 * vy1 * vx1;
        int i00 = cy0 * 96 + cx0, i01 = cy0 * 96 + cx1;
        int i10 = cy1 * 96 + cx0, i11 = cy1 * 96 + cx1;

        const float* xg = xb + (size_t)(g * 8) * 9216;
        alignas(16) ushort vals[8];
#pragma unroll
        for (int cg = 0; cg < 8; ++cg) {
            const float* p = xg + (size_t)cg * 9216;
            float v = (w00 * p[i00] + w01 * p[i01] +
                       w10 * p[i10] + w11 * p[i11]) * mm;
            vals[cg] = f2bf(v);
        }
        *(int4v*)(s_cols + ln * 40 + wv * 8) = *(int4v*)vals;
        __syncthreads();

        bf16x8 bfrag = *(const bf16x8*)(s_cols + (wv * 16 + l15) * 40 + l4 * 8);
#pragma unroll
        for (int mt = 0; mt < 4; ++mt) {
            bf16x8 af = *(const bf16x8*)(wdp +
                ((size_t)((ks * 4 + l4) * 64) + mt * 16 + l15) * 8);
            acc[mt] = __builtin_amdgcn_mfma_f32_16x16x32_bf16(
                af, bfrag, acc[mt], 0, 0, 0);
        }
    }

    int pxe = px0 + wv * 16 + l15;
    size_t pb = (size_t)b * 9216 + pxe;
#pragma unroll
    for (int mt = 0; mt < 4; ++mt) {
        ushort hb[4];
#pragma unroll
        for (int r = 0; r < 4; ++r) {
            int oc = mt * 16 + l4 * 4 + r;
            hb[r] = f2bf(acc[mt][r] + bd[oc]);
        }
        uint2 pk;
        pk.x = (uint)hb[0] | ((uint)hb[1] << 16);
        pk.y = (uint)hb[2] | ((uint)hb[3] << 16);
        *(uint2*)(chl + pb * 128 + mt * 16 + l4 * 4) = pk;
    }
}

// ---------------------------------------------------------------------------
extern "C" void kernel_launch(void* const* d_in, const int* in_sizes, int n_in,
                              void* d_out, int out_size, void* d_ws, size_t ws_size,
                              hipStream_t stream) {
    const float* src0  = (const float*)d_in[0];
    const float* src1  = (const float*)d_in[1];
    const float* l_off = (const float*)d_in[2];
    const float* l_fea = (const float*)d_in[3];
    const float* w1 = (const float*)d_in[4];   const float* b1 = (const float*)d_in[5];
    const float* w2 = (const float*)d_in[6];   const float* b2 = (const float*)d_in[7];
    const float* w3 = (const float*)d_in[8];   const float* b3 = (const float*)d_in[9];
    const float* wom = (const float*)d_in[10]; const float* bom = (const float*)d_in[11];
    const float* wd = (const float*)d_in[12];  const float* bd = (const float*)d_in[13];
    const float* wf = (const float*)d_in[14];  const float* bf = (const float*)d_in[15];

    char* W = (char*)d_ws;
    ushort* xin1 = (ushort*)(W + 0);          // 9,437,184 B  [b][px][128]
    ushort* xin2 = (ushort*)(W + 9437184);    // 9,437,184 B  [b][px][128]
    ushort* xin3 = (ushort*)(W + 18874368);   // 4,718,592 B  [b][px][64]
    ushort* xoff = (ushort*)(W + 23592960);   // 4,718,592 B  [b][px][64]
    ushort* omb  = (ushort*)(W + 0);          // 15,925,248 B NCHW bf16 (over xin1+xin2)
    ushort* xin4 = (ushort*)(W + 18874368);   // 9,437,184 B  (over xin3+xoff, dead)
    ushort* w1p  = (ushort*)(W + 28311552);   // 147,456 B
    ushort* w2p  = (ushort*)(W + 28459008);   // 147,456 B
    ushort* w3p  = (ushort*)(W + 28606464);   //  73,728 B
    ushort* womp = (ushort*)(W + 28680192);   // 258,048 B
    ushort* wdp  = (ushort*)(W + 28938240);   //  73,728 B
    ushort* wfp  = (ushort*)(W + 29011968);   // 147,456 B -> total 29.16 MB

    float* out_off = (float*)d_out;
    float* out_fea = out_off + (size_t)4 * 64 * 9216;

    // weight prepacks
    prepw_k<<<36, 256, 0, stream>>>(w1, w1p, 128, 64, 64, 9216);
    prepw_k<<<36, 256, 0, stream>>>(w2, w2p, 128, 64, 64, 9216);
    prepw_k<<<18, 256, 0, stream>>>(w3, w3p, 64, 64, 64, 4608);
    prepw_k<<<63, 256, 0, stream>>>(wom, womp, 64, 216, 224, 16128);
    prepwd_k<<<18, 256, 0, stream>>>(wd, wdp);
    prepw_k<<<36, 256, 0, stream>>>(wf, wfp, 128, 64, 64, 9216);

    // activation packs
    pack2_k<<<dim3(144, 4), 256, 0, stream>>>(src0, src1, xin1);
    up2chl_k<<<dim3(144, 4), 256, 0, stream>>>(l_off, xin2, 128, 64, 2.0f);

    // conv1: xin1 -> xin2[0:64] (lrelu, ch-last)
    conv_mfma_k<128, true, false, false, true><<<dim3(144, 4, 1), 256, 0, stream>>>(
        xin1, w1p, b1, nullptr, nullptr, xin2, 64, 64, 128, 0);
    // conv2: xin2 -> xin3 (lrelu, ch-last)
    conv_mfma_k<128, true, false, false, true><<<dim3(144, 4, 1), 256, 0, stream>>>(
        xin2, w2p, b2, nullptr, nullptr, xin3, 64, 64, 64, 0);
    // conv3: xin3 -> out_off (fp32 NCHW) + xoff (ch-last)
    conv_mfma_k<64, true, true, false, true><<<dim3(144, 4, 1), 256, 0, stream>>>(
        xin3, w3p, b3, out_off, nullptr, xoff, 64, 64, 64, 0);
    // om conv: xoff -> omb (NCHW bf16, 216 of 224)
    conv_mfma_k<64, false, false, true, false><<<dim3(144, 4, 4), 256, 0, stream>>>(
        xoff, womp, bom, nullptr, omb, nullptr, 216, 224, 0, 0);
    // fused DCN -> xin4[0:64]
    dcn_fused_k<<<dim3(144, 4), 256, 0, stream>>>(src0, omb, wdp, bd, xin4);
    // up2(last_feature) -> xin4[64:128]
    up2chl_k<<<dim3(144, 4), 256, 0, stream>>>(l_fea, xin4, 128, 64, 1.0f);
    // fea conv: xin4 -> out_fea (fp32 NCHW, lrelu)
    conv_mfma_k<128, true, true, false, false><<<dim3(144, 4, 1), 256, 0, stream>>>(
        xin4, wfp, bf, out_fea, nullptr, nullptr, 64, 64, 0, 0);
}

// Round 3
// 214.717 us; speedup vs baseline: 8.0335x; 1.7935x over previous
//
#include <hip/hip_runtime.h>
#include <math.h>

typedef __attribute__((ext_vector_type(8))) short bf16x8;
typedef __attribute__((ext_vector_type(4))) float f32x4;
typedef __attribute__((ext_vector_type(4))) int int4v;

__device__ __forceinline__ ushort f2bf(float f) {
    union { float f; unsigned u; } v; v.f = f;
    unsigned r = (v.u + 0x7fffu + ((v.u >> 16) & 1u)) >> 16;
    return (ushort)r;
}
__device__ __forceinline__ float bf2f(ushort h) {
    union { unsigned u; float f; } v; v.u = ((unsigned)h) << 16;
    return v.f;
}

// ---------------------------------------------------------------------------
// Fused packs: z=0 pack concat(src0,src1)->xin1[px][128];
//              z=1 up2(l_off)*2 -> xin2[px][64:128]; z=2 up2(l_fea) -> xin4[px][64:128]
__global__ __launch_bounds__(256) void pack_combo_k(
        const float* __restrict__ s0, const float* __restrict__ s1,
        const float* __restrict__ lo, const float* __restrict__ lf,
        ushort* __restrict__ xin1, ushort* __restrict__ xin2,
        ushort* __restrict__ xin4) {
    int b = blockIdx.y;
    int z = blockIdx.z;
    int px = blockIdx.x * 64 + (threadIdx.x & 63);
    int u = threadIdx.x >> 6;
    if (z == 0) {
        for (int half = 0; half < 2; ++half) {
            int cg = u + half * 4;
            alignas(16) ushort tmp[16];
            for (int i = 0; i < 16; ++i) {
                int c = cg * 16 + i;
                float v = (c < 64) ? s0[((size_t)(b * 64 + c)) * 9216 + px]
                                   : s1[((size_t)(b * 64 + c - 64)) * 9216 + px];
                tmp[i] = f2bf(v);
            }
            ushort* dst = xin1 + ((size_t)(b * 9216) + px) * 128 + cg * 16;
            *(int4v*)dst = *(int4v*)&tmp[0];
            *(int4v*)(dst + 8) = *(int4v*)&tmp[8];
        }
    } else {
        const float* in = (z == 1) ? lo : lf;
        float scale = (z == 1) ? 2.0f : 1.0f;
        ushort* xo = (z == 1) ? xin2 : xin4;
        int y = px / 96, x = px % 96;
        float sy = fmaxf(y * 0.5f - 0.25f, 0.f);
        float sx = fmaxf(x * 0.5f - 0.25f, 0.f);
        int y0 = (int)sy, x0 = (int)sx;
        float ty = sy - (float)y0, tx = sx - (float)x0;
        int y1 = min(y0 + 1, 47), x1 = min(x0 + 1, 47);
        alignas(16) ushort tmp[16];
        for (int i = 0; i < 16; ++i) {
            int c = u * 16 + i;
            const float* p = in + ((size_t)(b * 64 + c)) * 2304;
            float v00 = p[y0 * 48 + x0], v01 = p[y0 * 48 + x1];
            float v10 = p[y1 * 48 + x0], v11 = p[y1 * 48 + x1];
            float v = (v00 * (1.f - tx) + v01 * tx) * (1.f - ty)
                    + (v10 * (1.f - tx) + v11 * tx) * ty;
            tmp[i] = f2bf(v * scale);
        }
        ushort* dst = xo + ((size_t)(b * 9216) + px) * 128 + 64 + u * 16;
        *(int4v*)dst = *(int4v*)&tmp[0];
        *(int4v*)(dst + 8) = *(int4v*)&tmp[8];
    }
}

// ---------------------------------------------------------------------------
// Fused weight prepack. Standard convs: w[oc][cin][3][3] -> wp[cc][kk][kg][CoutP][8]
__device__ __forceinline__ void prep_one(const float* __restrict__ w,
        ushort* __restrict__ wp, int u, int Cin, int CoutR, int CoutP) {
    int oc = u % CoutP; int t = u / CoutP;
    int kg = t & 3; t >>= 2;
    int kk = t % 9; int cc = t / 9;
    alignas(16) ushort tmp[8];
    for (int j = 0; j < 8; ++j) {
        int c = cc * 32 + kg * 8 + j;
        float v = (oc < CoutR) ? w[((size_t)oc * Cin + c) * 9 + kk] : 0.f;
        tmp[j] = f2bf(v);
    }
    *(int4v*)(wp + (size_t)u * 8) = *(int4v*)tmp;
}

__global__ __launch_bounds__(256) void prepack_all_k(
        const float* __restrict__ w1, const float* __restrict__ w2,
        const float* __restrict__ w3, const float* __restrict__ wom,
        const float* __restrict__ wd, const float* __restrict__ wf,
        ushort* __restrict__ w1p, ushort* __restrict__ w2p,
        ushort* __restrict__ w3p, ushort* __restrict__ womp,
        ushort* __restrict__ wdp, ushort* __restrict__ wfp) {
    int u = blockIdx.x * 256 + threadIdx.x;
    if (u < 9216) prep_one(w1, w1p, u, 128, 64, 64);
    else if (u < 18432) prep_one(w2, w2p, u - 9216, 128, 64, 64);
    else if (u < 23040) prep_one(w3, w3p, u - 18432, 64, 64, 64);
    else if (u < 39168) prep_one(wom, womp, u - 23040, 64, 216, 224);
    else if (u < 43776) {
        int v = u - 39168;                    // [gkk*64 + oc][8], k=(g*9+kk)*8+cg
        int oc = v & 63; int gkk = v >> 6;
        int g = gkk / 9, kk = gkk % 9;
        alignas(16) ushort tmp[8];
        for (int j = 0; j < 8; ++j)
            tmp[j] = f2bf(wd[((size_t)oc * 64 + g * 8 + j) * 9 + kk]);
        *(int4v*)(wdp + (size_t)v * 8) = *(int4v*)tmp;
    } else if (u < 52992) prep_one(wf, wfp, u - 43776, 128, 64, 64);
}

// ---------------------------------------------------------------------------
// MFMA 3x3 conv: per-wave MT*16 oc x 16 px, block = 8x8 px tile, MT oc-tiles.
// grid = (144, B, CoutP/(MT*16))
template<int CIN, int MT, bool LRELU, bool ST_F32, bool ST_NB16, bool ST_CHL>
__global__ __launch_bounds__(256) void conv_mfma_k(
        const ushort* __restrict__ xin,      // [b][9216][CIN] bf16
        const ushort* __restrict__ wp,       // [CIN/32][9][4][CoutP][8]
        const float* __restrict__ bias,
        float* __restrict__ outf,            // NCHW fp32
        ushort* __restrict__ outnb,          // NCHW bf16
        ushort* __restrict__ chl,            // ch-last bf16
        int CoutR, int CoutP, int ochs, int ocoff) {
    constexpr int CC = CIN / 32;
    constexpr int OCN = MT * 16;
    constexpr int WS = OCN + 4;               // padded oc stride
    __shared__ ushort s_act[4000];            // [100 px][40] (32 used + pad)
    __shared__ ushort s_w[36 * WS * 8];

    int tid = threadIdx.x;
    int wv = tid >> 6, ln = tid & 63;
    int l15 = ln & 15, l4 = ln >> 4;
    int tile = blockIdx.x;
    int b = blockIdx.y;
    int bx = (tile % 12) * 8, by = (tile / 12) * 8;
    int oc0 = blockIdx.z * OCN;

    int px_l = wv * 16 + l15;                 // px in 8x8 tile
    int py = px_l >> 3, pxx = px_l & 7;
    int b_base = (py * 10 + pxx) * 40 + l4 * 8;

    f32x4 acc[MT];
#pragma unroll
    for (int mt = 0; mt < MT; ++mt) acc[mt] = (f32x4){0.f, 0.f, 0.f, 0.f};

    for (int cc = 0; cc < CC; ++cc) {
        __syncthreads();
        // stage activation halo tile 10x10 x 32ch
        for (int i = tid; i < 400; i += 256) {
            int p = i >> 2, q = i & 3;
            int gy = by + (p / 10) - 1, gx = bx + (p % 10) - 1;
            int4v v = {0, 0, 0, 0};
            if ((unsigned)gy < 96u && (unsigned)gx < 96u)
                v = *(const int4v*)(xin +
                    ((size_t)(b * 9216 + gy * 96 + gx) * CIN + cc * 32 + q * 8));
            *(int4v*)(s_act + p * 40 + q * 8) = v;
        }
        // stage weights for this cc / oc block
        for (int i = tid; i < 36 * OCN; i += 256) {
            int kk = i / (4 * OCN); int r = i - kk * 4 * OCN;
            int kg = r / OCN; int oc = r - kg * OCN;
            int4v v = *(const int4v*)(wp +
                ((size_t)((cc * 9 + kk) * 4 + kg) * CoutP + oc0 + oc) * 8);
            *(int4v*)(s_w + ((kk * 4 + kg) * WS + oc) * 8) = v;
        }
        __syncthreads();
#pragma unroll
        for (int kk = 0; kk < 9; ++kk) {
            bf16x8 bfrag = *(const bf16x8*)(s_act + b_base +
                               ((kk / 3) * 10 + (kk % 3)) * 40);
#pragma unroll
            for (int mt = 0; mt < MT; ++mt) {
                bf16x8 af = *(const bf16x8*)(s_w +
                    ((kk * 4 + l4) * WS + mt * 16 + l15) * 8);
                acc[mt] = __builtin_amdgcn_mfma_f32_16x16x32_bf16(
                    af, bfrag, acc[mt], 0, 0, 0);
            }
        }
    }

    int gy = by + py, gx = bx + pxx;
    size_t pxg = (size_t)b * 9216 + gy * 96 + gx;
#pragma unroll
    for (int mt = 0; mt < MT; ++mt) {
        ushort hb[4];
#pragma unroll
        for (int r = 0; r < 4; ++r) {
            int oc = oc0 + mt * 16 + l4 * 4 + r;
            float v = acc[mt][r] + ((oc < CoutR) ? bias[oc] : 0.f);
            if (LRELU) v = (v >= 0.f) ? v : 0.1f * v;
            hb[r] = f2bf(v);
            if (ST_F32 && oc < CoutR)
                outf[((size_t)b * CoutR + oc) * 9216 + gy * 96 + gx] = v;
            if (ST_NB16 && oc < CoutR)
                outnb[((size_t)b * CoutR + oc) * 9216 + gy * 96 + gx] = hb[r];
        }
        if (ST_CHL) {
            uint2 pk;
            pk.x = (uint)hb[0] | ((uint)hb[1] << 16);
            pk.y = (uint)hb[2] | ((uint)hb[3] << 16);
            *(uint2*)(chl + pxg * ochs + ocoff + oc0 + mt * 16 + l4 * 4) = pk;
        }
    }
}

// ---------------------------------------------------------------------------
// Fused DCNv2, register-direct B fragments + split-K(2).
// Block = 256 thr = 4 waves: wave = (pxgrp = w>>1) x (khalf = w&1).
// Wave handles 16 px, 9 k-steps (36 gkk of 72). Lane l: px = l&15, gkk-sub = l>>4.
// grid = (9216/32 = 288, B)
__global__ __launch_bounds__(256) void dcn_fused_k(const float* __restrict__ x,
        const ushort* __restrict__ om, const ushort* __restrict__ wdp,
        const float* __restrict__ bd, ushort* __restrict__ chl) {
    __shared__ float s_red[2][64][17];
    int tid = threadIdx.x;
    int wv = tid >> 6, ln = tid & 63;
    int l15 = ln & 15, l4 = ln >> 4;
    int khalf = wv & 1, pxg = wv >> 1;
    int b = blockIdx.y;
    int px = blockIdx.x * 32 + pxg * 16 + l15;
    int y = px / 96, xx = px % 96;

    f32x4 acc[4];
#pragma unroll
    for (int mt = 0; mt < 4; ++mt) acc[mt] = (f32x4){0.f, 0.f, 0.f, 0.f};
    const float* xb = x + (size_t)b * 64 * 9216;

    for (int ks = 0; ks < 9; ++ks) {
        int gkk = khalf * 36 + ks * 4 + l4;   // per-lane
        int g = gkk / 9, kk = gkk % 9;
        size_t ob = ((size_t)b * 216 + gkk) * 9216 + px;
        float oy = bf2f(om[ob]);
        float ox = bf2f(om[ob + (size_t)72 * 9216]);
        float mm = bf2f(om[ob + (size_t)144 * 9216]);
        mm = 1.f / (1.f + __expf(-mm));
        float py = oy + (float)y + (float)(kk / 3 - 1);
        float pxf = ox + (float)xx + (float)(kk % 3 - 1);
        float yf = floorf(py), xf = floorf(pxf);
        float fy = py - yf, fx = pxf - xf;
        int iy0 = (int)yf, ix0 = (int)xf;
        int iy1 = iy0 + 1, ix1 = ix0 + 1;
        float vy0 = ((unsigned)iy0 < 96u) ? 1.f : 0.f;
        float vy1 = ((unsigned)iy1 < 96u) ? 1.f : 0.f;
        float vx0 = ((unsigned)ix0 < 96u) ? 1.f : 0.f;
        float vx1 = ((unsigned)ix1 < 96u) ? 1.f : 0.f;
        int cy0 = min(max(iy0, 0), 95), cy1 = min(max(iy1, 0), 95);
        int cx0 = min(max(ix0, 0), 95), cx1 = min(max(ix1, 0), 95);
        float w00 = (1.f - fy) * (1.f - fx) * vy0 * vx0;
        float w01 = (1.f - fy) * fx         * vy0 * vx1;
        float w10 = fy * (1.f - fx)         * vy1 * vx0;
        float w11 = fy * fx                 * vy1 * vx1;
        int i00 = cy0 * 96 + cx0, i01 = cy0 * 96 + cx1;
        int i10 = cy1 * 96 + cx0, i11 = cy1 * 96 + cx1;

        const float* xg = xb + (size_t)(g * 8) * 9216;
        union { ushort us[8]; bf16x8 v; } bu;
#pragma unroll
        for (int cg = 0; cg < 8; ++cg) {
            const float* p = xg + (size_t)cg * 9216;
            float v = (w00 * p[i00] + w01 * p[i01] +
                       w10 * p[i10] + w11 * p[i11]) * mm;
            bu.us[cg] = f2bf(v);
        }
#pragma unroll
        for (int mt = 0; mt < 4; ++mt) {
            bf16x8 af = *(const bf16x8*)(wdp +
                ((size_t)gkk * 64 + mt * 16 + l15) * 8);
            acc[mt] = __builtin_amdgcn_mfma_f32_16x16x32_bf16(
                af, bu.v, acc[mt], 0, 0, 0);
        }
    }

    // split-K reduce: khalf=1 writes, khalf=0 adds + stores
    if (khalf) {
#pragma unroll
        for (int mt = 0; mt < 4; ++mt)
#pragma unroll
            for (int r = 0; r < 4; ++r)
                s_red[pxg][ln][mt * 4 + r] = acc[mt][r];
    }
    __syncthreads();
    if (!khalf) {
        size_t pb = (size_t)b * 9216 + px;
#pragma unroll
        for (int mt = 0; mt < 4; ++mt) {
            ushort hb[4];
#pragma unroll
            for (int r = 0; r < 4; ++r) {
                int oc = mt * 16 + l4 * 4 + r;
                float v = acc[mt][r] + s_red[pxg][ln][mt * 4 + r] + bd[oc];
                hb[r] = f2bf(v);
            }
            uint2 pk;
            pk.x = (uint)hb[0] | ((uint)hb[1] << 16);
            pk.y = (uint)hb[2] | ((uint)hb[3] << 16);
            *(uint2*)(chl + pb * 128 + mt * 16 + l4 * 4) = pk;
        }
    }
}

// ---------------------------------------------------------------------------
extern "C" void kernel_launch(void* const* d_in, const int* in_sizes, int n_in,
                              void* d_out, int out_size, void* d_ws, size_t ws_size,
                              hipStream_t stream) {
    const float* src0  = (const float*)d_in[0];
    const float* src1  = (const float*)d_in[1];
    const float* l_off = (const float*)d_in[2];
    const float* l_fea = (const float*)d_in[3];
    const float* w1 = (const float*)d_in[4];   const float* b1 = (const float*)d_in[5];
    const float* w2 = (const float*)d_in[6];   const float* b2 = (const float*)d_in[7];
    const float* w3 = (const float*)d_in[8];   const float* b3 = (const float*)d_in[9];
    const float* wom = (const float*)d_in[10]; const float* bom = (const float*)d_in[11];
    const float* wd = (const float*)d_in[12];  const float* bd = (const float*)d_in[13];
    const float* wf = (const float*)d_in[14];  const float* bf = (const float*)d_in[15];

    char* W = (char*)d_ws;
    ushort* xin1 = (ushort*)(W + 0);          // 9,437,184 B  [b][px][128]
    ushort* xin2 = (ushort*)(W + 9437184);    // 9,437,184 B  [b][px][128]
    ushort* xin3 = (ushort*)(W + 18874368);   // 4,718,592 B  [b][px][64]
    ushort* xoff = (ushort*)(W + 23592960);   // 4,718,592 B  [b][px][64]
    ushort* omb  = (ushort*)(W + 28311552);   // 15,925,248 B NCHW bf16
    ushort* xin4 = (ushort*)(W + 44236800);   // 9,437,184 B  [b][px][128]
    ushort* w1p  = (ushort*)(W + 53673984);   // 147,456 B
    ushort* w2p  = (ushort*)(W + 53821440);   // 147,456 B
    ushort* w3p  = (ushort*)(W + 53968896);   //  73,728 B
    ushort* womp = (ushort*)(W + 54042624);   // 258,048 B
    ushort* wdp  = (ushort*)(W + 54300672);   //  73,728 B
    ushort* wfp  = (ushort*)(W + 54374400);   // 147,456 B -> 54.5 MB total

    float* out_off = (float*)d_out;
    float* out_fea = out_off + (size_t)4 * 64 * 9216;

    // fused weight prepack (52992 units)
    prepack_all_k<<<207, 256, 0, stream>>>(w1, w2, w3, wom, wd, wf,
                                           w1p, w2p, w3p, womp, wdp, wfp);
    // fused input packs: xin1, xin2[64:128] (lo*2), xin4[64:128] (lf)
    pack_combo_k<<<dim3(144, 4, 3), 256, 0, stream>>>(
        src0, src1, l_off, l_fea, xin1, xin2, xin4);

    // conv1: xin1 -> xin2[0:64] (lrelu, ch-last)
    conv_mfma_k<128, 2, true, false, false, true><<<dim3(144, 4, 2), 256, 0, stream>>>(
        xin1, w1p, b1, nullptr, nullptr, xin2, 64, 64, 128, 0);
    // conv2: xin2 -> xin3 (lrelu, ch-last)
    conv_mfma_k<128, 2, true, false, false, true><<<dim3(144, 4, 2), 256, 0, stream>>>(
        xin2, w2p, b2, nullptr, nullptr, xin3, 64, 64, 64, 0);
    // conv3: xin3 -> out_off (fp32 NCHW) + xoff (ch-last)
    conv_mfma_k<64, 2, true, true, false, true><<<dim3(144, 4, 2), 256, 0, stream>>>(
        xin3, w3p, b3, out_off, nullptr, xoff, 64, 64, 64, 0);
    // om conv: xoff -> omb (NCHW bf16, 216 of 224)
    conv_mfma_k<64, 2, false, false, true, false><<<dim3(144, 4, 7), 256, 0, stream>>>(
        xoff, womp, bom, nullptr, omb, nullptr, 216, 224, 0, 0);
    // fused DCN -> xin4[0:64]
    dcn_fused_k<<<dim3(288, 4), 256, 0, stream>>>(src0, omb, wdp, bd, xin4);
    // fea conv: xin4 -> out_fea (fp32 NCHW, lrelu)
    conv_mfma_k<128, 2, true, true, false, false><<<dim3(144, 4, 2), 256, 0, stream>>>(
        xin4, wfp, bf, out_fea, nullptr, nullptr, 64, 64, 0, 0);
}

// Round 4
// 170.511 us; speedup vs baseline: 10.1162x; 1.2593x over previous
//
#include <hip/hip_runtime.h>
#include <math.h>

typedef __attribute__((ext_vector_type(8))) short bf16x8;
typedef __attribute__((ext_vector_type(4))) float f32x4;
typedef __attribute__((ext_vector_type(4))) int int4v;

__device__ __forceinline__ ushort f2bf(float f) {
    union { float f; unsigned u; } v; v.f = f;
    unsigned r = (v.u + 0x7fffu + ((v.u >> 16) & 1u)) >> 16;
    return (ushort)r;
}
__device__ __forceinline__ float bf2f(ushort h) {
    union { unsigned u; float f; } v; v.u = ((unsigned)h) << 16;
    return v.f;
}

// ---------------------------------------------------------------------------
// Fused packs: z=0 pack concat(src0,src1)->xin1[px][128];
//              z=1 up2(l_off)*2 -> xin2[px][64:128]; z=2 up2(l_fea) -> xin4[px][64:128]
__global__ __launch_bounds__(256) void pack_combo_k(
        const float* __restrict__ s0, const float* __restrict__ s1,
        const float* __restrict__ lo, const float* __restrict__ lf,
        ushort* __restrict__ xin1, ushort* __restrict__ xin2,
        ushort* __restrict__ xin4) {
    int b = blockIdx.y;
    int z = blockIdx.z;
    int px = blockIdx.x * 64 + (threadIdx.x & 63);
    int u = threadIdx.x >> 6;
    if (z == 0) {
        for (int half = 0; half < 2; ++half) {
            int cg = u + half * 4;
            alignas(16) ushort tmp[16];
            for (int i = 0; i < 16; ++i) {
                int c = cg * 16 + i;
                float v = (c < 64) ? s0[((size_t)(b * 64 + c)) * 9216 + px]
                                   : s1[((size_t)(b * 64 + c - 64)) * 9216 + px];
                tmp[i] = f2bf(v);
            }
            ushort* dst = xin1 + ((size_t)(b * 9216) + px) * 128 + cg * 16;
            *(int4v*)dst = *(int4v*)&tmp[0];
            *(int4v*)(dst + 8) = *(int4v*)&tmp[8];
        }
    } else {
        const float* in = (z == 1) ? lo : lf;
        float scale = (z == 1) ? 2.0f : 1.0f;
        ushort* xo = (z == 1) ? xin2 : xin4;
        int y = px / 96, x = px % 96;
        float sy = fmaxf(y * 0.5f - 0.25f, 0.f);
        float sx = fmaxf(x * 0.5f - 0.25f, 0.f);
        int y0 = (int)sy, x0 = (int)sx;
        float ty = sy - (float)y0, tx = sx - (float)x0;
        int y1 = min(y0 + 1, 47), x1 = min(x0 + 1, 47);
        alignas(16) ushort tmp[16];
        for (int i = 0; i < 16; ++i) {
            int c = u * 16 + i;
            const float* p = in + ((size_t)(b * 64 + c)) * 2304;
            float v00 = p[y0 * 48 + x0], v01 = p[y0 * 48 + x1];
            float v10 = p[y1 * 48 + x0], v11 = p[y1 * 48 + x1];
            float v = (v00 * (1.f - tx) + v01 * tx) * (1.f - ty)
                    + (v10 * (1.f - tx) + v11 * tx) * ty;
            tmp[i] = f2bf(v * scale);
        }
        ushort* dst = xo + ((size_t)(b * 9216) + px) * 128 + 64 + u * 16;
        *(int4v*)dst = *(int4v*)&tmp[0];
        *(int4v*)(dst + 8) = *(int4v*)&tmp[8];
    }
}

// ---------------------------------------------------------------------------
// Fused weight prepack. Standard convs: w[oc][cin][3][3] -> wp[cc][kk][kg][CoutP][8]
__device__ __forceinline__ void prep_one(const float* __restrict__ w,
        ushort* __restrict__ wp, int u, int Cin, int CoutR, int CoutP) {
    int oc = u % CoutP; int t = u / CoutP;
    int kg = t & 3; t >>= 2;
    int kk = t % 9; int cc = t / 9;
    alignas(16) ushort tmp[8];
    for (int j = 0; j < 8; ++j) {
        int c = cc * 32 + kg * 8 + j;
        float v = (oc < CoutR) ? w[((size_t)oc * Cin + c) * 9 + kk] : 0.f;
        tmp[j] = f2bf(v);
    }
    *(int4v*)(wp + (size_t)u * 8) = *(int4v*)tmp;
}

__global__ __launch_bounds__(256) void prepack_all_k(
        const float* __restrict__ w1, const float* __restrict__ w2,
        const float* __restrict__ w3, const float* __restrict__ wom,
        const float* __restrict__ wd, const float* __restrict__ wf,
        ushort* __restrict__ w1p, ushort* __restrict__ w2p,
        ushort* __restrict__ w3p, ushort* __restrict__ womp,
        ushort* __restrict__ wdp, ushort* __restrict__ wfp) {
    int u = blockIdx.x * 256 + threadIdx.x;
    if (u < 9216) prep_one(w1, w1p, u, 128, 64, 64);
    else if (u < 18432) prep_one(w2, w2p, u - 9216, 128, 64, 64);
    else if (u < 23040) prep_one(w3, w3p, u - 18432, 64, 64, 64);
    else if (u < 39168) prep_one(wom, womp, u - 23040, 64, 216, 224);
    else if (u < 43776) {
        int v = u - 39168;                    // [gkk*64 + oc][8], k=(g*9+kk)*8+cg
        int oc = v & 63; int gkk = v >> 6;
        int g = gkk / 9, kk = gkk % 9;
        alignas(16) ushort tmp[8];
        for (int j = 0; j < 8; ++j)
            tmp[j] = f2bf(wd[((size_t)oc * 64 + g * 8 + j) * 9 + kk]);
        *(int4v*)(wdp + (size_t)v * 8) = *(int4v*)tmp;
    } else if (u < 52992) prep_one(wf, wfp, u - 43776, 128, 64, 64);
}

// ---------------------------------------------------------------------------
// MFMA 3x3 conv: per-wave MT*16 oc x 16 px, block = 8x8 px tile, MT oc-tiles.
// grid = (144, B, CoutP/(MT*16))
template<int CIN, int MT, bool LRELU, bool ST_F32, bool ST_NB16, bool ST_CHL>
__global__ __launch_bounds__(256) void conv_mfma_k(
        const ushort* __restrict__ xin,      // [b][9216][CIN] bf16
        const ushort* __restrict__ wp,       // [CIN/32][9][4][CoutP][8]
        const float* __restrict__ bias,
        float* __restrict__ outf,            // NCHW fp32
        ushort* __restrict__ outnb,          // NCHW bf16
        ushort* __restrict__ chl,            // ch-last bf16
        int CoutR, int CoutP, int ochs, int ocoff) {
    constexpr int CC = CIN / 32;
    constexpr int OCN = MT * 16;
    constexpr int WS = OCN + 4;               // padded oc stride
    __shared__ ushort s_act[4000];            // [100 px][40] (32 used + pad)
    __shared__ ushort s_w[36 * WS * 8];

    int tid = threadIdx.x;
    int wv = tid >> 6, ln = tid & 63;
    int l15 = ln & 15, l4 = ln >> 4;
    int tile = blockIdx.x;
    int b = blockIdx.y;
    int bx = (tile % 12) * 8, by = (tile / 12) * 8;
    int oc0 = blockIdx.z * OCN;

    int px_l = wv * 16 + l15;                 // px in 8x8 tile
    int py = px_l >> 3, pxx = px_l & 7;
    int b_base = (py * 10 + pxx) * 40 + l4 * 8;

    f32x4 acc[MT];
#pragma unroll
    for (int mt = 0; mt < MT; ++mt) acc[mt] = (f32x4){0.f, 0.f, 0.f, 0.f};

    for (int cc = 0; cc < CC; ++cc) {
        __syncthreads();
        // stage activation halo tile 10x10 x 32ch
        for (int i = tid; i < 400; i += 256) {
            int p = i >> 2, q = i & 3;
            int gy = by + (p / 10) - 1, gx = bx + (p % 10) - 1;
            int4v v = {0, 0, 0, 0};
            if ((unsigned)gy < 96u && (unsigned)gx < 96u)
                v = *(const int4v*)(xin +
                    ((size_t)(b * 9216 + gy * 96 + gx) * CIN + cc * 32 + q * 8));
            *(int4v*)(s_act + p * 40 + q * 8) = v;
        }
        // stage weights for this cc / oc block
        for (int i = tid; i < 36 * OCN; i += 256) {
            int kk = i / (4 * OCN); int r = i - kk * 4 * OCN;
            int kg = r / OCN; int oc = r - kg * OCN;
            int4v v = *(const int4v*)(wp +
                ((size_t)((cc * 9 + kk) * 4 + kg) * CoutP + oc0 + oc) * 8);
            *(int4v*)(s_w + ((kk * 4 + kg) * WS + oc) * 8) = v;
        }
        __syncthreads();
#pragma unroll
        for (int kk = 0; kk < 9; ++kk) {
            bf16x8 bfrag = *(const bf16x8*)(s_act + b_base +
                               ((kk / 3) * 10 + (kk % 3)) * 40);
#pragma unroll
            for (int mt = 0; mt < MT; ++mt) {
                bf16x8 af = *(const bf16x8*)(s_w +
                    ((kk * 4 + l4) * WS + mt * 16 + l15) * 8);
                acc[mt] = __builtin_amdgcn_mfma_f32_16x16x32_bf16(
                    af, bfrag, acc[mt], 0, 0, 0);
            }
        }
    }

    int gy = by + py, gx = bx + pxx;
    size_t pxg = (size_t)b * 9216 + gy * 96 + gx;
#pragma unroll
    for (int mt = 0; mt < MT; ++mt) {
        ushort hb[4];
#pragma unroll
        for (int r = 0; r < 4; ++r) {
            int oc = oc0 + mt * 16 + l4 * 4 + r;
            float v = acc[mt][r] + ((oc < CoutR) ? bias[oc] : 0.f);
            if (LRELU) v = (v >= 0.f) ? v : 0.1f * v;
            hb[r] = f2bf(v);
            if (ST_F32 && oc < CoutR)
                outf[((size_t)b * CoutR + oc) * 9216 + gy * 96 + gx] = v;
            if (ST_NB16 && oc < CoutR)
                outnb[((size_t)b * CoutR + oc) * 9216 + gy * 96 + gx] = hb[r];
        }
        if (ST_CHL) {
            uint2 pk;
            pk.x = (uint)hb[0] | ((uint)hb[1] << 16);
            pk.y = (uint)hb[2] | ((uint)hb[3] << 16);
            *(uint2*)(chl + pxg * ochs + ocoff + oc0 + mt * 16 + l4 * 4) = pk;
        }
    }
}

// ---------------------------------------------------------------------------
// Fused DCNv2, register-direct B fragments + split-K(2).
// Sampling source = xin1 ch-last bf16: one 16B load per corner (8 contiguous cg).
// Block = 256 thr = 4 waves: wave = (pxgrp = w>>1) x (khalf = w&1).
// Wave handles 16 px, 9 k-steps (36 gkk of 72). Lane l: px = l&15, gkk-sub = l>>4.
// grid = (9216/32 = 288, B)
__global__ __launch_bounds__(256, 4) void dcn_fused_k(
        const ushort* __restrict__ xcl,      // xin1 [b][px][128], src0 in [0:64]
        const ushort* __restrict__ om, const ushort* __restrict__ wdp,
        const float* __restrict__ bd, ushort* __restrict__ chl) {
    __shared__ float s_red[2][64][17];
    int tid = threadIdx.x;
    int wv = tid >> 6, ln = tid & 63;
    int l15 = ln & 15, l4 = ln >> 4;
    int khalf = wv & 1, pxg = wv >> 1;
    int b = blockIdx.y;
    int px = blockIdx.x * 32 + pxg * 16 + l15;
    int y = px / 96, xx = px % 96;

    f32x4 acc[4];
#pragma unroll
    for (int mt = 0; mt < 4; ++mt) acc[mt] = (f32x4){0.f, 0.f, 0.f, 0.f};
    const ushort* xb = xcl + (size_t)b * 9216 * 128;

#pragma unroll
    for (int ks = 0; ks < 9; ++ks) {
        int gkk = khalf * 36 + ks * 4 + l4;   // per-lane
        int g = gkk / 9, kk = gkk % 9;
        size_t ob = ((size_t)b * 216 + gkk) * 9216 + px;
        float oy = bf2f(om[ob]);
        float ox = bf2f(om[ob + (size_t)72 * 9216]);
        float mm = bf2f(om[ob + (size_t)144 * 9216]);
        mm = 1.f / (1.f + __expf(-mm));
        float py = oy + (float)y + (float)(kk / 3 - 1);
        float pxf = ox + (float)xx + (float)(kk % 3 - 1);
        float yf = floorf(py), xf = floorf(pxf);
        float fy = py - yf, fx = pxf - xf;
        int iy0 = (int)yf, ix0 = (int)xf;
        int iy1 = iy0 + 1, ix1 = ix0 + 1;
        float vy0 = ((unsigned)iy0 < 96u) ? 1.f : 0.f;
        float vy1 = ((unsigned)iy1 < 96u) ? 1.f : 0.f;
        float vx0 = ((unsigned)ix0 < 96u) ? 1.f : 0.f;
        float vx1 = ((unsigned)ix1 < 96u) ? 1.f : 0.f;
        int cy0 = min(max(iy0, 0), 95), cy1 = min(max(iy1, 0), 95);
        int cx0 = min(max(ix0, 0), 95), cx1 = min(max(ix1, 0), 95);
        // fold modulation into bilinear weights
        float w00 = (1.f - fy) * (1.f - fx) * vy0 * vx0 * mm;
        float w01 = (1.f - fy) * fx         * vy0 * vx1 * mm;
        float w10 = fy * (1.f - fx)         * vy1 * vx0 * mm;
        float w11 = fy * fx                 * vy1 * vx1 * mm;
        int i00 = cy0 * 96 + cx0, i01 = cy0 * 96 + cx1;
        int i10 = cy1 * 96 + cx0, i11 = cy1 * 96 + cx1;

        const ushort* xg = xb + g * 8;        // channel slice of group g
        union { int4v v; ushort us[8]; } r00, r01, r10, r11;
        r00.v = *(const int4v*)(xg + (size_t)i00 * 128);
        r01.v = *(const int4v*)(xg + (size_t)i01 * 128);
        r10.v = *(const int4v*)(xg + (size_t)i10 * 128);
        r11.v = *(const int4v*)(xg + (size_t)i11 * 128);

        union { ushort us[8]; bf16x8 v; } bu;
#pragma unroll
        for (int j = 0; j < 8; ++j) {
            float v = w00 * bf2f(r00.us[j]) + w01 * bf2f(r01.us[j]) +
                      w10 * bf2f(r10.us[j]) + w11 * bf2f(r11.us[j]);
            bu.us[j] = f2bf(v);
        }
#pragma unroll
        for (int mt = 0; mt < 4; ++mt) {
            bf16x8 af = *(const bf16x8*)(wdp +
                ((size_t)gkk * 64 + mt * 16 + l15) * 8);
            acc[mt] = __builtin_amdgcn_mfma_f32_16x16x32_bf16(
                af, bu.v, acc[mt], 0, 0, 0);
        }
    }

    // split-K reduce: khalf=1 writes, khalf=0 adds + stores
    if (khalf) {
#pragma unroll
        for (int mt = 0; mt < 4; ++mt)
#pragma unroll
            for (int r = 0; r < 4; ++r)
                s_red[pxg][ln][mt * 4 + r] = acc[mt][r];
    }
    __syncthreads();
    if (!khalf) {
        size_t pb = (size_t)b * 9216 + px;
#pragma unroll
        for (int mt = 0; mt < 4; ++mt) {
            ushort hb[4];
#pragma unroll
            for (int r = 0; r < 4; ++r) {
                int oc = mt * 16 + l4 * 4 + r;
                float v = acc[mt][r] + s_red[pxg][ln][mt * 4 + r] + bd[oc];
                hb[r] = f2bf(v);
            }
            uint2 pk;
            pk.x = (uint)hb[0] | ((uint)hb[1] << 16);
            pk.y = (uint)hb[2] | ((uint)hb[3] << 16);
            *(uint2*)(chl + pb * 128 + mt * 16 + l4 * 4) = pk;
        }
    }
}

// ---------------------------------------------------------------------------
extern "C" void kernel_launch(void* const* d_in, const int* in_sizes, int n_in,
                              void* d_out, int out_size, void* d_ws, size_t ws_size,
                              hipStream_t stream) {
    const float* src0  = (const float*)d_in[0];
    const float* src1  = (const float*)d_in[1];
    const float* l_off = (const float*)d_in[2];
    const float* l_fea = (const float*)d_in[3];
    const float* w1 = (const float*)d_in[4];   const float* b1 = (const float*)d_in[5];
    const float* w2 = (const float*)d_in[6];   const float* b2 = (const float*)d_in[7];
    const float* w3 = (const float*)d_in[8];   const float* b3 = (const float*)d_in[9];
    const float* wom = (const float*)d_in[10]; const float* bom = (const float*)d_in[11];
    const float* wd = (const float*)d_in[12];  const float* bd = (const float*)d_in[13];
    const float* wf = (const float*)d_in[14];  const float* bf = (const float*)d_in[15];

    char* W = (char*)d_ws;
    ushort* xin1 = (ushort*)(W + 0);          // 9,437,184 B  [b][px][128]
    ushort* xin2 = (ushort*)(W + 9437184);    // 9,437,184 B  [b][px][128]
    ushort* xin3 = (ushort*)(W + 18874368);   // 4,718,592 B  [b][px][64]
    ushort* xoff = (ushort*)(W + 23592960);   // 4,718,592 B  [b][px][64]
    ushort* omb  = (ushort*)(W + 28311552);   // 15,925,248 B NCHW bf16
    ushort* xin4 = (ushort*)(W + 44236800);   // 9,437,184 B  [b][px][128]
    ushort* w1p  = (ushort*)(W + 53673984);   // 147,456 B
    ushort* w2p  = (ushort*)(W + 53821440);   // 147,456 B
    ushort* w3p  = (ushort*)(W + 53968896);   //  73,728 B
    ushort* womp = (ushort*)(W + 54042624);   // 258,048 B
    ushort* wdp  = (ushort*)(W + 54300672);   //  73,728 B
    ushort* wfp  = (ushort*)(W + 54374400);   // 147,456 B -> 54.5 MB total

    float* out_off = (float*)d_out;
    float* out_fea = out_off + (size_t)4 * 64 * 9216;

    // fused weight prepack (52992 units)
    prepack_all_k<<<207, 256, 0, stream>>>(w1, w2, w3, wom, wd, wf,
                                           w1p, w2p, w3p, womp, wdp, wfp);
    // fused input packs: xin1, xin2[64:128] (lo*2), xin4[64:128] (lf)
    pack_combo_k<<<dim3(144, 4, 3), 256, 0, stream>>>(
        src0, src1, l_off, l_fea, xin1, xin2, xin4);

    // conv1: xin1 -> xin2[0:64] (lrelu, ch-last)
    conv_mfma_k<128, 2, true, false, false, true><<<dim3(144, 4, 2), 256, 0, stream>>>(
        xin1, w1p, b1, nullptr, nullptr, xin2, 64, 64, 128, 0);
    // conv2: xin2 -> xin3 (lrelu, ch-last)
    conv_mfma_k<128, 2, true, false, false, true><<<dim3(144, 4, 2), 256, 0, stream>>>(
        xin2, w2p, b2, nullptr, nullptr, xin3, 64, 64, 64, 0);
    // conv3: xin3 -> out_off (fp32 NCHW) + xoff (ch-last)
    conv_mfma_k<64, 2, true, true, false, true><<<dim3(144, 4, 2), 256, 0, stream>>>(
        xin3, w3p, b3, out_off, nullptr, xoff, 64, 64, 64, 0);
    // om conv: xoff -> omb (NCHW bf16, 216 of 224)
    conv_mfma_k<64, 2, false, false, true, false><<<dim3(144, 4, 7), 256, 0, stream>>>(
        xoff, womp, bom, nullptr, omb, nullptr, 216, 224, 0, 0);
    // fused DCN -> xin4[0:64]  (samples from xin1 ch-last bf16)
    dcn_fused_k<<<dim3(288, 4), 256, 0, stream>>>(xin1, omb, wdp, bd, xin4);
    // fea conv: xin4 -> out_fea (fp32 NCHW, lrelu)
    conv_mfma_k<128, 2, true, true, false, false><<<dim3(144, 4, 2), 256, 0, stream>>>(
        xin4, wfp, bf, out_fea, nullptr, nullptr, 64, 64, 0, 0);
}